// Round 3
// baseline (462.532 us; speedup 1.0000x reference)
//
#include <hip/hip_runtime.h>

typedef __attribute__((ext_vector_type(8))) short short8;
typedef __attribute__((ext_vector_type(4))) float f32x4;
typedef unsigned short u16;
typedef unsigned int u32;

#define B_ 32
#define S_ 578
#define D_ 1024
#define H_ 16
#define DH_ 64
#define M_ 18496
#define MP2_ 18688                     /* 73*256: padded rows for 256-row GEMM tiles */
#define N_ 3072
#define K_ 1024
#define ST_ 640                        /* padded seq len for e-major V rows */
#define BHROWS_ (B_ * H_ * S_ + 64)    /* +64 pad for attn tail-tile over-read */
#define SCALE2 0.18033688011112042f    /* 0.125 * log2(e) */
#define CMAX 16.0f

__device__ __forceinline__ u16 f2bf(float x) {
  u32 u = __float_as_uint(x);
  u = (u + 0x7fffu + ((u >> 16) & 1u)) >> 16;
  return (u16)u;
}

__device__ __forceinline__ void gload_lds16(const u16* g, u16* l) {
  __builtin_amdgcn_global_load_lds((const __attribute__((address_space(1))) void*)g,
                                   (__attribute__((address_space(3))) void*)l, 16, 0, 0);
}

// ---------------- prep: hidden fp32 -> bf16 (zero-fill tile pad rows) ----------------
__global__ __launch_bounds__(256) void cvt_hidden(const float* __restrict__ in, u16* __restrict__ o) {
  long i = ((long)blockIdx.x * 256 + threadIdx.x) * 8;
  if (i >= (long)M_ * D_) {
    short8 z = {0, 0, 0, 0, 0, 0, 0, 0};
    *(short8*)(o + i) = z;
    return;
  }
  float4 f0 = *(const float4*)(in + i);
  float4 f1 = *(const float4*)(in + i + 4);
  short8 v;
  u16* p = (u16*)&v;
  p[0] = f2bf(f0.x); p[1] = f2bf(f0.y); p[2] = f2bf(f0.z); p[3] = f2bf(f0.w);
  p[4] = f2bf(f1.x); p[5] = f2bf(f1.y); p[6] = f2bf(f1.z); p[7] = f2bf(f1.w);
  *(short8*)(o + i) = v;
}

// ---------------- prep: W[H,D,DH] -> Wt[N,K] bf16 (B^T layout) ----------------
__global__ __launch_bounds__(256) void wt_kernel(const float* __restrict__ Wq, const float* __restrict__ Wk,
                                                 const float* __restrict__ Wv, u16* __restrict__ Wt) {
  const int d0 = blockIdx.x * 64;
  const int h = blockIdx.y;
  const int qkv = blockIdx.z;
  const float* W = (qkv == 0) ? Wq : ((qkv == 1) ? Wk : Wv);
  __shared__ float tile[64][65];
  const int t = threadIdx.x;
  {
    int e = t & 63, dr = t >> 6;
#pragma unroll
    for (int p = 0; p < 16; ++p) {
      int dd = dr + p * 4;
      tile[dd][e] = W[((long)h * D_ + d0 + dd) * DH_ + e];
    }
  }
  __syncthreads();
  {
    int dd = t & 63, er = t >> 6;
#pragma unroll
    for (int p = 0; p < 16; ++p) {
      int ee = er + p * 4;
      long n = (long)qkv * 1024 + h * 64 + ee;
      Wt[n * K_ + d0 + dd] = f2bf(tile[dd][ee]);
    }
  }
}

// ---------------- prep: pack biases into [3072] fp32 ----------------
__global__ __launch_bounds__(256) void bias_kernel(const float* __restrict__ bq, const float* __restrict__ bk,
                                                   const float* __restrict__ bv, float* __restrict__ bias) {
  int i = blockIdx.x * 256 + threadIdx.x;
  if (i < 3072) {
    const float* src = (i < 1024) ? bq : ((i < 2048) ? bk : bv);
    bias[i] = src[i & 1023];
  }
}

// ---------------- QKV GEMM: 256x256 tile, BK=64, 4-phase/K-tile counted-vmcnt pipeline ----------------
// 512 threads / 8 waves (2M x 4N), per-wave 128x64 = acc[8][4].
// LDS: 2 dbuf x (A 256x64 + B 256x64) bf16 = 128 KiB, stored as two 256x32 k-slabs each.
// Per phase: {ds_read frags || stage ONE half-slab (2 gload_lds/lane) -> barrier ->
//             lgkmcnt(0) -> setprio(1) -> 16 MFMA -> setprio(0) -> [counted vmcnt] -> barrier}.
// Derived waits (vmem retires in order; 2 loads per stage; queue traced per wave):
//   entering tile t: outstanding = [A(t).k1, B(t).k1] = 4
//   P1 stages A(t+1).k0 -> 6 ; P2 stages B(t+1).k0 -> 8
//   P2-end: vmcnt(4)  (retires A(t).k1 + B(t).k1 -- P3 reads BOTH)
//   P3 stages A(t+1).k1 -> 6 ; P4 stages B(t+1).k1 -> 8
//   P4-end: vmcnt(4)  (retires A(t+1).k0 + B(t+1).k0 -- next P1/P2 read them)
// Drain tile: P2-end vmcnt(0), P4-end none. Never 0 mid-loop; 2 half-slabs always in flight.

__device__ __forceinline__ void stage_slab(const u16* __restrict__ g, u16* l, int tid, int k0) {
  const int r = tid >> 2;                               // row 0..127 within half
  const int gch = (tid & 3) ^ ((tid >> 3) & 3);         // swizzled global k-chunk for phys slot tid&3
  const u16* src = g + (long)r * K_ + k0 + gch * 8;
  gload_lds16(src, l + tid * 8);                        // rows 0..127
  gload_lds16(src + 128L * K_, l + 4096 + tid * 8);     // rows 128..255
}

template <int CUR, bool STG, int V2, int V4>
__device__ __forceinline__ void tile_step(const u16* __restrict__ Ag, const u16* __restrict__ Bg,
                                          u16 (*Ab)[2][8192], u16 (*Bb)[2][8192],
                                          f32x4 (&acc)[8][4], int tid, int arow, int brow, int sw, int k2) {
  const short8* Av0 = (const short8*)Ab[CUR][0];
  const short8* Av1 = (const short8*)Ab[CUR][1];
  const short8* Bv0 = (const short8*)Bb[CUR][0];
  const short8* Bv1 = (const short8*)Bb[CUR][1];
  short8 a[8], b0, b1, b2, b3;

  // ---- P1: ds-read A.k0 frags + B.k0 lo ; stage next A.k0 ----
#pragma unroll
  for (int mi = 0; mi < 8; ++mi) a[mi] = Av0[(arow + mi * 16) * 4 + sw];
  b0 = Bv0[brow * 4 + sw];
  b1 = Bv0[(brow + 16) * 4 + sw];
  if constexpr (STG) stage_slab(Ag, &Ab[CUR ^ 1][0][0], tid, k2);
  __builtin_amdgcn_s_barrier();
  asm volatile("s_waitcnt lgkmcnt(0)" ::: "memory");
  __builtin_amdgcn_sched_barrier(0);
  __builtin_amdgcn_s_setprio(1);
#pragma unroll
  for (int mi = 0; mi < 8; ++mi) {
    acc[mi][0] = __builtin_amdgcn_mfma_f32_16x16x32_bf16(a[mi], b0, acc[mi][0], 0, 0, 0);
    acc[mi][1] = __builtin_amdgcn_mfma_f32_16x16x32_bf16(a[mi], b1, acc[mi][1], 0, 0, 0);
  }
  __builtin_amdgcn_s_setprio(0);
  __builtin_amdgcn_s_barrier();
  __builtin_amdgcn_sched_barrier(0);

  // ---- P2: ds-read B.k0 hi ; stage next B.k0 ; vmcnt(V2) ----
  b2 = Bv0[(brow + 32) * 4 + sw];
  b3 = Bv0[(brow + 48) * 4 + sw];
  if constexpr (STG) stage_slab(Bg, &Bb[CUR ^ 1][0][0], tid, k2);
  __builtin_amdgcn_s_barrier();
  asm volatile("s_waitcnt lgkmcnt(0)" ::: "memory");
  __builtin_amdgcn_sched_barrier(0);
  __builtin_amdgcn_s_setprio(1);
#pragma unroll
  for (int mi = 0; mi < 8; ++mi) {
    acc[mi][2] = __builtin_amdgcn_mfma_f32_16x16x32_bf16(a[mi], b2, acc[mi][2], 0, 0, 0);
    acc[mi][3] = __builtin_amdgcn_mfma_f32_16x16x32_bf16(a[mi], b3, acc[mi][3], 0, 0, 0);
  }
  __builtin_amdgcn_s_setprio(0);
  if constexpr (V2 == 4) asm volatile("s_waitcnt vmcnt(4)" ::: "memory");
  else if constexpr (V2 == 0) asm volatile("s_waitcnt vmcnt(0)" ::: "memory");
  __builtin_amdgcn_s_barrier();
  __builtin_amdgcn_sched_barrier(0);

  // ---- P3: ds-read A.k1 frags + B.k1 lo ; stage next A.k1 ----
#pragma unroll
  for (int mi = 0; mi < 8; ++mi) a[mi] = Av1[(arow + mi * 16) * 4 + sw];
  b0 = Bv1[brow * 4 + sw];
  b1 = Bv1[(brow + 16) * 4 + sw];
  if constexpr (STG) stage_slab(Ag, &Ab[CUR ^ 1][1][0], tid, k2 + 32);
  __builtin_amdgcn_s_barrier();
  asm volatile("s_waitcnt lgkmcnt(0)" ::: "memory");
  __builtin_amdgcn_sched_barrier(0);
  __builtin_amdgcn_s_setprio(1);
#pragma unroll
  for (int mi = 0; mi < 8; ++mi) {
    acc[mi][0] = __builtin_amdgcn_mfma_f32_16x16x32_bf16(a[mi], b0, acc[mi][0], 0, 0, 0);
    acc[mi][1] = __builtin_amdgcn_mfma_f32_16x16x32_bf16(a[mi], b1, acc[mi][1], 0, 0, 0);
  }
  __builtin_amdgcn_s_setprio(0);
  __builtin_amdgcn_s_barrier();
  __builtin_amdgcn_sched_barrier(0);

  // ---- P4: ds-read B.k1 hi ; stage next B.k1 ; vmcnt(V4) ----
  b2 = Bv1[(brow + 32) * 4 + sw];
  b3 = Bv1[(brow + 48) * 4 + sw];
  if constexpr (STG) stage_slab(Bg, &Bb[CUR ^ 1][1][0], tid, k2 + 32);
  __builtin_amdgcn_s_barrier();
  asm volatile("s_waitcnt lgkmcnt(0)" ::: "memory");
  __builtin_amdgcn_sched_barrier(0);
  __builtin_amdgcn_s_setprio(1);
#pragma unroll
  for (int mi = 0; mi < 8; ++mi) {
    acc[mi][2] = __builtin_amdgcn_mfma_f32_16x16x32_bf16(a[mi], b2, acc[mi][2], 0, 0, 0);
    acc[mi][3] = __builtin_amdgcn_mfma_f32_16x16x32_bf16(a[mi], b3, acc[mi][3], 0, 0, 0);
  }
  __builtin_amdgcn_s_setprio(0);
  if constexpr (V4 == 4) asm volatile("s_waitcnt vmcnt(4)" ::: "memory");
  __builtin_amdgcn_s_barrier();
  __builtin_amdgcn_sched_barrier(0);
}

__global__ __launch_bounds__(512, 2) void qkv_gemm(const u16* __restrict__ A, const u16* __restrict__ Bt,
                                                   const float* __restrict__ bias,
                                                   u16* __restrict__ qb, u16* __restrict__ kb,
                                                   u16* __restrict__ vbt) {
  __shared__ alignas(16) u16 Ab[2][2][8192];   // [dbuf][k-slab][256 rows x 32 k]
  __shared__ alignas(16) u16 Bb[2][2][8192];
  const int tid = threadIdx.x, wid = tid >> 6, lane = tid & 63, quad = lane >> 4, l16 = lane & 15;
  const int wr = wid >> 2, wc = wid & 3;

  // bijective XCD swizzle over 876 blocks (876 % 8 != 0 -> m204 variant)
  const int nwg = 73 * 12;
  const int qq = nwg >> 3, rr = nwg & 7;  // 109, 4
  int xcd = blockIdx.x & 7, loc = blockIdx.x >> 3;
  int wg = (xcd < rr ? xcd * (qq + 1) : rr * (qq + 1) + (xcd - rr) * qq) + loc;
  const int mt = wg / 12, nt = wg - mt * 12;
  const long m0 = (long)mt * 256, n0 = (long)nt * 256;
  const u16* Ag = A + m0 * K_;
  const u16* Bg = Bt + n0 * K_;

  f32x4 acc[8][4];
#pragma unroll
  for (int mi = 0; mi < 8; ++mi)
#pragma unroll
    for (int ni = 0; ni < 4; ++ni) { f32x4 z = {0.f, 0.f, 0.f, 0.f}; acc[mi][ni] = z; }

  const int sw = quad ^ ((l16 >> 1) & 3);  // frag-read phys chunk (inverse of staging swizzle)
  const int arow = wr * 128 + l16;
  const int brow = wc * 64 + l16;

  // prologue: stage tile 0 fully (issue order A.k0, B.k0, A.k1, B.k1 = vmcnt accounting order)
  stage_slab(Ag, &Ab[0][0][0], tid, 0);
  stage_slab(Bg, &Bb[0][0][0], tid, 0);
  stage_slab(Ag, &Ab[0][1][0], tid, 32);
  stage_slab(Bg, &Bb[0][1][0], tid, 32);
  asm volatile("s_waitcnt vmcnt(4)" ::: "memory");   // k0 halves landed; k1 halves may fly
  __builtin_amdgcn_s_barrier();
  __builtin_amdgcn_sched_barrier(0);

  // 16 K-tiles of BK=64; tiles 0..14 stage tile t+1, tile 15 drains
#pragma unroll 1
  for (int t = 0; t < 14; t += 2) {
    tile_step<0, true, 4, 4>(Ag, Bg, Ab, Bb, acc, tid, arow, brow, sw, (t + 1) * 64);
    tile_step<1, true, 4, 4>(Ag, Bg, Ab, Bb, acc, tid, arow, brow, sw, (t + 2) * 64);
  }
  tile_step<0, true, 4, 4>(Ag, Bg, Ab, Bb, acc, tid, arow, brow, sw, 15 * 64);
  tile_step<1, false, 0, -1>(Ag, Bg, Ab, Bb, acc, tid, arow, brow, sw, 0);

  // epilogue: += bias; scatter q/k to [B,H,S,DH], v to e-major [B,H,DH,ST_]
  const long nb = n0 + wc * 64;
  const int h = (int)((nb >> 6) & 15);
  const int qkvsel = (int)(nb >> 10);
  float bv4[4];
#pragma unroll
  for (int ni = 0; ni < 4; ++ni) bv4[ni] = bias[nb + ni * 16 + l16];

  if (qkvsel == 2) {
#pragma unroll
    for (int mi = 0; mi < 8; ++mi) {
#pragma unroll
      for (int r = 0; r < 4; ++r) {
        long m = m0 + wr * 128 + mi * 16 + quad * 4 + r;
        if (m < M_) {
          unsigned bi = (unsigned)m / (unsigned)S_;
          unsigned si = (unsigned)m - bi * (unsigned)S_;
          long base = ((long)(bi * H_ + h) * DH_) * ST_ + si;
#pragma unroll
          for (int ni = 0; ni < 4; ++ni) {
            float v = acc[mi][ni][r] + bv4[ni];
            vbt[base + (long)(ni * 16 + l16) * ST_] = f2bf(v);
          }
        }
      }
    }
  } else {
    u16* dst = (qkvsel == 0) ? qb : kb;
#pragma unroll
    for (int mi = 0; mi < 8; ++mi) {
#pragma unroll
      for (int r = 0; r < 4; ++r) {
        long m = m0 + wr * 128 + mi * 16 + quad * 4 + r;
        if (m < M_) {
          unsigned bi = (unsigned)m / (unsigned)S_;
          unsigned si = (unsigned)m - bi * (unsigned)S_;
          long base = ((long)(bi * H_ + h) * S_ + si) * DH_;
#pragma unroll
          for (int ni = 0; ni < 4; ++ni) {
            float v = acc[mi][ni][r] + bv4[ni];
            dst[base + ni * 16 + l16] = f2bf(v);
          }
        }
      }
    }
  }
}

// ---------------- flash attention, fixed-max softmax, full gload_lds staging ----------------
__global__ __launch_bounds__(256) void attn_kernel(const u16* __restrict__ qb, const u16* __restrict__ kb,
                                                   const u16* __restrict__ vbt, float* __restrict__ out) {
  __shared__ alignas(16) u16 Ks[64 * 64];
  __shared__ alignas(16) u16 Vs[64 * 64];
  __shared__ alignas(16) u16 Ps[4 * 16 * 72];
  const int tid = threadIdx.x, wave = tid >> 6, lane = tid & 63, quad = lane >> 4, l16 = lane & 15;
  const int qt = blockIdx.x, h = blockIdx.y, b = blockIdx.z;
  const long bh = (long)b * H_ + h;
  const u16* qp = qb + bh * S_ * DH_;
  const u16* kp = kb + bh * S_ * DH_;
  const u16* vtp = vbt + bh * DH_ * ST_;
  const int q0 = qt * 64;

  short8 qf0, qf1;
  {
    int row = q0 + wave * 16 + l16;
    const short8* qv = (const short8*)(qp + (long)row * DH_);
    qf0 = qv[quad];
    qf1 = qv[4 + quad];
  }

  f32x4 O[4];
#pragma unroll
  for (int et = 0; et < 4; ++et) { f32x4 z = {0.f, 0.f, 0.f, 0.f}; O[et] = z; }
  float lp[4] = {0.f, 0.f, 0.f, 0.f};

  const int srow0 = tid >> 3;
  const int slot = tid & 7;
  const int s0 = quad ^ (l16 & 7);

  for (int kt = 0; kt < 10; ++kt) {
    const int t0 = kt * 64;
    __syncthreads();
#pragma unroll
    for (int p = 0; p < 2; ++p) {
      int row = srow0 + 32 * p;
      int gch = slot ^ (row & 7);
      gload_lds16(kp + (long)(t0 + row) * DH_ + gch * 8, &Ks[(tid + 256 * p) * 8]);
      gload_lds16(vtp + (long)row * ST_ + t0 + gch * 8, &Vs[(tid + 256 * p) * 8]);
    }
    __syncthreads();

    float p[4][4];
    const short8* Kv8 = (const short8*)Ks;
#pragma unroll
    for (int jt = 0; jt < 4; ++jt) {
      f32x4 sacc = {0.f, 0.f, 0.f, 0.f};
      short8 kf0 = Kv8[(16 * jt + l16) * 8 + s0];
      short8 kf1 = Kv8[(16 * jt + l16) * 8 + ((quad + 4) ^ (l16 & 7))];
      sacc = __builtin_amdgcn_mfma_f32_16x16x32_bf16(qf0, kf0, sacc, 0, 0, 0);
      sacc = __builtin_amdgcn_mfma_f32_16x16x32_bf16(qf1, kf1, sacc, 0, 0, 0);
      bool valid = (t0 + 16 * jt + l16) < S_;
#pragma unroll
      for (int r = 0; r < 4; ++r) {
        float e = valid ? exp2f(sacc[r] * SCALE2 - CMAX) : 0.f;
        p[jt][r] = e;
        lp[r] += e;
      }
    }

    u16* Pw = Ps + wave * 16 * 72;
#pragma unroll
    for (int jt = 0; jt < 4; ++jt)
#pragma unroll
      for (int r = 0; r < 4; ++r)
        Pw[(quad * 4 + r) * 72 + 16 * jt + l16] = f2bf(p[jt][r]);

    const short8* Pv8 = (const short8*)(Ps + wave * 16 * 72);
    const short8* Vv8 = (const short8*)Vs;
#pragma unroll
    for (int ks = 0; ks < 2; ++ks) {
      short8 pa = Pv8[l16 * 9 + ks * 4 + quad];
#pragma unroll
      for (int et = 0; et < 4; ++et) {
        short8 vf = Vv8[(16 * et + l16) * 8 + ((ks * 4 + quad) ^ (l16 & 7))];
        O[et] = __builtin_amdgcn_mfma_f32_16x16x32_bf16(pa, vf, O[et], 0, 0, 0);
      }
    }
  }

  float inv[4];
#pragma unroll
  for (int r = 0; r < 4; ++r) {
    float s = lp[r];
    s += __shfl_xor(s, 1);
    s += __shfl_xor(s, 2);
    s += __shfl_xor(s, 4);
    s += __shfl_xor(s, 8);
    inv[r] = 1.0f / s;
  }
#pragma unroll
  for (int et = 0; et < 4; ++et)
#pragma unroll
    for (int r = 0; r < 4; ++r) {
      int s = q0 + wave * 16 + quad * 4 + r;
      if (s < S_) out[((long)b * S_ + s) * (H_ * DH_) + (long)h * DH_ + et * 16 + l16] = O[et][r] * inv[r];
    }
}

extern "C" void kernel_launch(void* const* d_in, const int* in_sizes, int n_in,
                              void* d_out, int out_size, void* d_ws, size_t ws_size,
                              hipStream_t stream) {
  const float* hs = (const float*)d_in[0];
  const float* Wq = (const float*)d_in[1];
  const float* bq = (const float*)d_in[2];
  const float* Wk = (const float*)d_in[3];
  const float* bk = (const float*)d_in[4];
  const float* Wv = (const float*)d_in[5];
  const float* bv = (const float*)d_in[6];
  float* out = (float*)d_out;

  u16* Abf = (u16*)d_ws;                                   // [MP2_, K_] bf16
  u16* Wt = Abf + (size_t)MP2_ * K_;                       // [N_, K_] bf16
  float* bias = (float*)(Wt + (size_t)N_ * K_);            // [N_] fp32
  u16* qb = (u16*)(bias + N_);                             // [BHROWS_, DH_] bf16
  u16* kb = qb + (size_t)BHROWS_ * DH_;                    // [BHROWS_, DH_] bf16
  u16* vbt = kb + (size_t)BHROWS_ * DH_;                   // [B*H, DH_, ST_] bf16 (e-major)

  cvt_hidden<<<dim3(9344), dim3(256), 0, stream>>>(hs, Abf);
  wt_kernel<<<dim3(16, 16, 3), dim3(256), 0, stream>>>(Wq, Wk, Wv, Wt);
  bias_kernel<<<dim3(12), dim3(256), 0, stream>>>(bq, bk, bv, bias);
  qkv_gemm<<<dim3(876), dim3(512), 0, stream>>>(Abf, Wt, bias, qb, kb, vbt);
  attn_kernel<<<dim3(10, 16, 32), dim3(256), 0, stream>>>(qb, kb, vbt, out);
}

// Round 5
// 451.781 us; speedup vs baseline: 1.0238x; 1.0238x over previous
//
#include <hip/hip_runtime.h>

typedef __attribute__((ext_vector_type(8))) short short8;
typedef __attribute__((ext_vector_type(4))) float f32x4;
typedef unsigned short u16;
typedef unsigned int u32;

#define B_ 32
#define S_ 578
#define D_ 1024
#define H_ 16
#define DH_ 64
#define M_ 18496
#define MP2_ 18688                     /* 146*128: padded rows for 128-row GEMM tiles */
#define N_ 3072
#define K_ 1024
#define ST_ 640                        /* padded seq len for e-major V rows */
#define BHROWS_ (B_ * H_ * S_ + 64)    /* +64 pad for attn tail-tile over-read */
#define SCALE2 0.18033688011112042f    /* 0.125 * log2(e) */
#define CMAX 16.0f

__device__ __forceinline__ u16 f2bf(float x) {
  u32 u = __float_as_uint(x);
  u = (u + 0x7fffu + ((u >> 16) & 1u)) >> 16;
  return (u16)u;
}

__device__ __forceinline__ void gload_lds16(const u16* g, u16* l) {
  __builtin_amdgcn_global_load_lds((const __attribute__((address_space(1))) void*)g,
                                   (__attribute__((address_space(3))) void*)l, 16, 0, 0);
}

// ---------------- prep: hidden fp32 -> bf16 (zero-fill tile pad rows) ----------------
__global__ __launch_bounds__(256) void cvt_hidden(const float* __restrict__ in, u16* __restrict__ o) {
  long i = ((long)blockIdx.x * 256 + threadIdx.x) * 8;
  if (i >= (long)M_ * D_) {
    short8 z = {0, 0, 0, 0, 0, 0, 0, 0};
    *(short8*)(o + i) = z;
    return;
  }
  float4 f0 = *(const float4*)(in + i);
  float4 f1 = *(const float4*)(in + i + 4);
  short8 v;
  u16* p = (u16*)&v;
  p[0] = f2bf(f0.x); p[1] = f2bf(f0.y); p[2] = f2bf(f0.z); p[3] = f2bf(f0.w);
  p[4] = f2bf(f1.x); p[5] = f2bf(f1.y); p[6] = f2bf(f1.z); p[7] = f2bf(f1.w);
  *(short8*)(o + i) = v;
}

// ---------------- prep: W[H,D,DH] -> Wt[N,K] bf16 (B^T layout) ----------------
__global__ __launch_bounds__(256) void wt_kernel(const float* __restrict__ Wq, const float* __restrict__ Wk,
                                                 const float* __restrict__ Wv, u16* __restrict__ Wt) {
  const int d0 = blockIdx.x * 64;
  const int h = blockIdx.y;
  const int qkv = blockIdx.z;
  const float* W = (qkv == 0) ? Wq : ((qkv == 1) ? Wk : Wv);
  __shared__ float tile[64][65];
  const int t = threadIdx.x;
  {
    int e = t & 63, dr = t >> 6;
#pragma unroll
    for (int p = 0; p < 16; ++p) {
      int dd = dr + p * 4;
      tile[dd][e] = W[((long)h * D_ + d0 + dd) * DH_ + e];
    }
  }
  __syncthreads();
  {
    int dd = t & 63, er = t >> 6;
#pragma unroll
    for (int p = 0; p < 16; ++p) {
      int ee = er + p * 4;
      long n = (long)qkv * 1024 + h * 64 + ee;
      Wt[n * K_ + d0 + dd] = f2bf(tile[dd][ee]);
    }
  }
}

// ---------------- prep: pack biases into [3072] fp32 ----------------
__global__ __launch_bounds__(256) void bias_kernel(const float* __restrict__ bq, const float* __restrict__ bk,
                                                   const float* __restrict__ bv, float* __restrict__ bias) {
  int i = blockIdx.x * 256 + threadIdx.x;
  if (i < 3072) {
    const float* src = (i < 1024) ? bq : ((i < 2048) ? bk : bv);
    bias[i] = src[i & 1023];
  }
}

// ---------------- QKV GEMM: 128x256 tile, BK=32, dbuf, 2 blocks/CU (TLP covers the drain) ----------------
// 512 threads / 8 waves (2M x 4N), per-wave 64x64 = acc[4][4] (64 VGPR) -> <=128 VGPR total
// -> 16 waves/CU = 2 blocks/CU. LDS: dbuf x (A 128x32 + B 256x32) bf16 = 48 KiB (2 blocks = 96 <=160).
// One __syncthreads per K-tile (drains vmcnt per HIP semantics -- correct by construction);
// the co-resident block's waves fill the MFMA pipe during the drain (m114 mechanism, m97's 874 TF).
// BN=256 keeps A re-reads at 12x (FETCH ~186MB, vs 514MB at BN=128).

__device__ __forceinline__ void stage_a(const u16* __restrict__ g, u16* l, int tid, int k0) {
  const int r = tid >> 2;                               // row 0..127
  const int gch = (tid & 3) ^ ((tid >> 3) & 3);         // swizzled global k-chunk for phys slot tid&3
  gload_lds16(g + (long)r * K_ + k0 + gch * 8, l + tid * 8);
}

__device__ __forceinline__ void stage_b(const u16* __restrict__ g, u16* l, int tid, int k0) {
  const int r = tid >> 2;
  const int gch = (tid & 3) ^ ((tid >> 3) & 3);
  const u16* src = g + (long)r * K_ + k0 + gch * 8;
  gload_lds16(src, l + tid * 8);                        // rows 0..127
  gload_lds16(src + 128L * K_, l + 4096 + tid * 8);     // rows 128..255
}

__global__ __launch_bounds__(512, 4) void qkv_gemm(const u16* __restrict__ A, const u16* __restrict__ Bt,
                                                   const float* __restrict__ bias,
                                                   u16* __restrict__ qb, u16* __restrict__ kb,
                                                   u16* __restrict__ vbt) {
  __shared__ alignas(16) u16 Ab[2][128 * 32];   // 8 KB each
  __shared__ alignas(16) u16 Bb[2][256 * 32];   // 16 KB each
  const int tid = threadIdx.x, wid = tid >> 6, lane = tid & 63, quad = lane >> 4, l16 = lane & 15;
  const int wr = wid >> 2, wc = wid & 3;        // 2M x 4N wave grid

  // XCD swizzle: 1752 blocks = 8 * 219 exactly
  const int wg = (blockIdx.x & 7) * 219 + (blockIdx.x >> 3);
  const int mt = wg / 12, nt = wg - mt * 12;
  const long m0 = (long)mt * 128, n0 = (long)nt * 256;
  const u16* Ag = A + m0 * K_;
  const u16* Bg = Bt + n0 * K_;

  f32x4 acc[4][4];
#pragma unroll
  for (int mi = 0; mi < 4; ++mi)
#pragma unroll
    for (int ni = 0; ni < 4; ++ni) { f32x4 z = {0.f, 0.f, 0.f, 0.f}; acc[mi][ni] = z; }

  const int sw = quad ^ ((l16 >> 1) & 3);  // frag-read phys chunk (inverse of staging swizzle)
  const int arow = wr * 64 + l16;
  const int brow = wc * 64 + l16;

  // prologue: stage K-tile 0 into buf0
  stage_a(Ag, Ab[0], tid, 0);
  stage_b(Bg, Bb[0], tid, 0);
  __syncthreads();

#pragma unroll 1
  for (int t = 0; t < 32; t += 2) {
    // step 0: compute buf0 (tile t), stage tile t+1 -> buf1
    {
      stage_a(Ag, Ab[1], tid, (t + 1) * 32);
      stage_b(Bg, Bb[1], tid, (t + 1) * 32);
      const short8* Av = (const short8*)Ab[0];
      const short8* Bv = (const short8*)Bb[0];
      short8 a[4], b[4];
#pragma unroll
      for (int mi = 0; mi < 4; ++mi) a[mi] = Av[(arow + mi * 16) * 4 + sw];
#pragma unroll
      for (int ni = 0; ni < 4; ++ni) b[ni] = Bv[(brow + ni * 16) * 4 + sw];
#pragma unroll
      for (int mi = 0; mi < 4; ++mi)
#pragma unroll
        for (int ni = 0; ni < 4; ++ni)
          acc[mi][ni] = __builtin_amdgcn_mfma_f32_16x16x32_bf16(a[mi], b[ni], acc[mi][ni], 0, 0, 0);
      __syncthreads();
    }
    // step 1: compute buf1 (tile t+1), stage tile t+2 -> buf0 (unless done)
    {
      if (t + 2 < 32) {
        stage_a(Ag, Ab[0], tid, (t + 2) * 32);
        stage_b(Bg, Bb[0], tid, (t + 2) * 32);
      }
      const short8* Av = (const short8*)Ab[1];
      const short8* Bv = (const short8*)Bb[1];
      short8 a[4], b[4];
#pragma unroll
      for (int mi = 0; mi < 4; ++mi) a[mi] = Av[(arow + mi * 16) * 4 + sw];
#pragma unroll
      for (int ni = 0; ni < 4; ++ni) b[ni] = Bv[(brow + ni * 16) * 4 + sw];
#pragma unroll
      for (int mi = 0; mi < 4; ++mi)
#pragma unroll
        for (int ni = 0; ni < 4; ++ni)
          acc[mi][ni] = __builtin_amdgcn_mfma_f32_16x16x32_bf16(a[mi], b[ni], acc[mi][ni], 0, 0, 0);
      __syncthreads();
    }
  }

  // epilogue: += bias; scatter q/k to [B,H,S,DH], v to e-major [B,H,DH,ST_]
  // wave's 64-wide n-block is head-aligned -> h and qkv are wave-uniform
  // (proven scalar scatter path from the round-3-passing kernel, adapted to wr*64)
  const long nb = n0 + wc * 64;
  const int h = (int)((nb >> 6) & 15);
  const int qkvsel = (int)(nb >> 10);
  float bv4[4];
#pragma unroll
  for (int ni = 0; ni < 4; ++ni) bv4[ni] = bias[nb + ni * 16 + l16];

  if (qkvsel == 2) {
#pragma unroll
    for (int mi = 0; mi < 4; ++mi) {
#pragma unroll
      for (int r = 0; r < 4; ++r) {
        long m = m0 + wr * 64 + mi * 16 + quad * 4 + r;
        if (m < M_) {
          unsigned bi = (unsigned)m / (unsigned)S_;
          unsigned si = (unsigned)m - bi * (unsigned)S_;
          long base = ((long)(bi * H_ + h) * DH_) * ST_ + si;
#pragma unroll
          for (int ni = 0; ni < 4; ++ni) {
            float v = acc[mi][ni][r] + bv4[ni];
            vbt[base + (long)(ni * 16 + l16) * ST_] = f2bf(v);
          }
        }
      }
    }
  } else {
    u16* dst = (qkvsel == 0) ? qb : kb;
#pragma unroll
    for (int mi = 0; mi < 4; ++mi) {
#pragma unroll
      for (int r = 0; r < 4; ++r) {
        long m = m0 + wr * 64 + mi * 16 + quad * 4 + r;
        if (m < M_) {
          unsigned bi = (unsigned)m / (unsigned)S_;
          unsigned si = (unsigned)m - bi * (unsigned)S_;
          long base = ((long)(bi * H_ + h) * S_ + si) * DH_;
#pragma unroll
          for (int ni = 0; ni < 4; ++ni) {
            float v = acc[mi][ni][r] + bv4[ni];
            dst[base + ni * 16 + l16] = f2bf(v);
          }
        }
      }
    }
  }
}

// ---------------- flash attention, fixed-max softmax, full gload_lds staging ----------------
__global__ __launch_bounds__(256) void attn_kernel(const u16* __restrict__ qb, const u16* __restrict__ kb,
                                                   const u16* __restrict__ vbt, float* __restrict__ out) {
  __shared__ alignas(16) u16 Ks[64 * 64];
  __shared__ alignas(16) u16 Vs[64 * 64];
  __shared__ alignas(16) u16 Ps[4 * 16 * 72];
  const int tid = threadIdx.x, wave = tid >> 6, lane = tid & 63, quad = lane >> 4, l16 = lane & 15;
  const int qt = blockIdx.x, h = blockIdx.y, b = blockIdx.z;
  const long bh = (long)b * H_ + h;
  const u16* qp = qb + bh * S_ * DH_;
  const u16* kp = kb + bh * S_ * DH_;
  const u16* vtp = vbt + bh * DH_ * ST_;
  const int q0 = qt * 64;

  short8 qf0, qf1;
  {
    int row = q0 + wave * 16 + l16;
    const short8* qv = (const short8*)(qp + (long)row * DH_);
    qf0 = qv[quad];
    qf1 = qv[4 + quad];
  }

  f32x4 O[4];
#pragma unroll
  for (int et = 0; et < 4; ++et) { f32x4 z = {0.f, 0.f, 0.f, 0.f}; O[et] = z; }
  float lp[4] = {0.f, 0.f, 0.f, 0.f};

  const int srow0 = tid >> 3;
  const int slot = tid & 7;
  const int s0 = quad ^ (l16 & 7);

  for (int kt = 0; kt < 10; ++kt) {
    const int t0 = kt * 64;
    __syncthreads();
#pragma unroll
    for (int p = 0; p < 2; ++p) {
      int row = srow0 + 32 * p;
      int gch = slot ^ (row & 7);
      gload_lds16(kp + (long)(t0 + row) * DH_ + gch * 8, &Ks[(tid + 256 * p) * 8]);
      gload_lds16(vtp + (long)row * ST_ + t0 + gch * 8, &Vs[(tid + 256 * p) * 8]);
    }
    __syncthreads();

    float p[4][4];
    const short8* Kv8 = (const short8*)Ks;
#pragma unroll
    for (int jt = 0; jt < 4; ++jt) {
      f32x4 sacc = {0.f, 0.f, 0.f, 0.f};
      short8 kf0 = Kv8[(16 * jt + l16) * 8 + s0];
      short8 kf1 = Kv8[(16 * jt + l16) * 8 + ((quad + 4) ^ (l16 & 7))];
      sacc = __builtin_amdgcn_mfma_f32_16x16x32_bf16(qf0, kf0, sacc, 0, 0, 0);
      sacc = __builtin_amdgcn_mfma_f32_16x16x32_bf16(qf1, kf1, sacc, 0, 0, 0);
      bool valid = (t0 + 16 * jt + l16) < S_;
#pragma unroll
      for (int r = 0; r < 4; ++r) {
        float e = valid ? exp2f(sacc[r] * SCALE2 - CMAX) : 0.f;
        p[jt][r] = e;
        lp[r] += e;
      }
    }

    u16* Pw = Ps + wave * 16 * 72;
#pragma unroll
    for (int jt = 0; jt < 4; ++jt)
#pragma unroll
      for (int r = 0; r < 4; ++r)
        Pw[(quad * 4 + r) * 72 + 16 * jt + l16] = f2bf(p[jt][r]);

    const short8* Pv8 = (const short8*)(Ps + wave * 16 * 72);
    const short8* Vv8 = (const short8*)Vs;
#pragma unroll
    for (int ks = 0; ks < 2; ++ks) {
      short8 pa = Pv8[l16 * 9 + ks * 4 + quad];
#pragma unroll
      for (int et = 0; et < 4; ++et) {
        short8 vf = Vv8[(16 * et + l16) * 8 + ((ks * 4 + quad) ^ (l16 & 7))];
        O[et] = __builtin_amdgcn_mfma_f32_16x16x32_bf16(pa, vf, O[et], 0, 0, 0);
      }
    }
  }

  float inv[4];
#pragma unroll
  for (int r = 0; r < 4; ++r) {
    float s = lp[r];
    s += __shfl_xor(s, 1);
    s += __shfl_xor(s, 2);
    s += __shfl_xor(s, 4);
    s += __shfl_xor(s, 8);
    inv[r] = 1.0f / s;
  }
#pragma unroll
  for (int et = 0; et < 4; ++et)
#pragma unroll
    for (int r = 0; r < 4; ++r) {
      int s = q0 + wave * 16 + quad * 4 + r;
      if (s < S_) out[((long)b * S_ + s) * (H_ * DH_) + (long)h * DH_ + et * 16 + l16] = O[et][r] * inv[r];
    }
}

extern "C" void kernel_launch(void* const* d_in, const int* in_sizes, int n_in,
                              void* d_out, int out_size, void* d_ws, size_t ws_size,
                              hipStream_t stream) {
  const float* hs = (const float*)d_in[0];
  const float* Wq = (const float*)d_in[1];
  const float* bq = (const float*)d_in[2];
  const float* Wk = (const float*)d_in[3];
  const float* bk = (const float*)d_in[4];
  const float* Wv = (const float*)d_in[5];
  const float* bv = (const float*)d_in[6];
  float* out = (float*)d_out;

  u16* Abf = (u16*)d_ws;                                   // [MP2_, K_] bf16
  u16* Wt = Abf + (size_t)MP2_ * K_;                       // [N_, K_] bf16
  float* bias = (float*)(Wt + (size_t)N_ * K_);            // [N_] fp32
  u16* qb = (u16*)(bias + N_);                             // [BHROWS_, DH_] bf16
  u16* kb = qb + (size_t)BHROWS_ * DH_;                    // [BHROWS_, DH_] bf16
  u16* vbt = kb + (size_t)BHROWS_ * DH_;                   // [B*H, DH_, ST_] bf16 (e-major)

  cvt_hidden<<<dim3(9344), dim3(256), 0, stream>>>(hs, Abf);
  wt_kernel<<<dim3(16, 16, 3), dim3(256), 0, stream>>>(Wq, Wk, Wv, Wt);
  bias_kernel<<<dim3(12), dim3(256), 0, stream>>>(bq, bk, bv, bias);
  qkv_gemm<<<dim3(1752), dim3(512), 0, stream>>>(Abf, Wt, bias, qb, kb, vbt);
  attn_kernel<<<dim3(10, 16, 32), dim3(256), 0, stream>>>(qb, kb, vbt, out);
}

// Round 6
// 440.456 us; speedup vs baseline: 1.0501x; 1.0257x over previous
//
#include <hip/hip_runtime.h>

typedef __attribute__((ext_vector_type(8))) short short8;
typedef __attribute__((ext_vector_type(4))) float f32x4;
typedef unsigned short u16;
typedef unsigned int u32;

#define B_ 32
#define S_ 578
#define D_ 1024
#define H_ 16
#define DH_ 64
#define M_ 18496
#define MP2_ 18688                     /* 146*128: padded rows for 128-row GEMM tiles */
#define N_ 3072
#define K_ 1024
#define ST_ 640                        /* padded seq len for e-major V rows */
#define BHROWS_ (B_ * H_ * S_ + 64)    /* +64 pad for attn tail-tile over-read */
#define SCALE2 0.18033688011112042f    /* 0.125 * log2(e) */
#define CMAX 16.0f

__device__ __forceinline__ u16 f2bf(float x) {
  u32 u = __float_as_uint(x);
  u = (u + 0x7fffu + ((u >> 16) & 1u)) >> 16;
  return (u16)u;
}

__device__ __forceinline__ void gload_lds16(const u16* g, u16* l) {
  __builtin_amdgcn_global_load_lds((const __attribute__((address_space(1))) void*)g,
                                   (__attribute__((address_space(3))) void*)l, 16, 0, 0);
}

// ---------------- prep: hidden fp32 -> bf16 (zero-fill tile pad rows) ----------------
__global__ __launch_bounds__(256) void cvt_hidden(const float* __restrict__ in, u16* __restrict__ o) {
  long i = ((long)blockIdx.x * 256 + threadIdx.x) * 8;
  if (i >= (long)M_ * D_) {
    short8 z = {0, 0, 0, 0, 0, 0, 0, 0};
    *(short8*)(o + i) = z;
    return;
  }
  float4 f0 = *(const float4*)(in + i);
  float4 f1 = *(const float4*)(in + i + 4);
  short8 v;
  u16* p = (u16*)&v;
  p[0] = f2bf(f0.x); p[1] = f2bf(f0.y); p[2] = f2bf(f0.z); p[3] = f2bf(f0.w);
  p[4] = f2bf(f1.x); p[5] = f2bf(f1.y); p[6] = f2bf(f1.z); p[7] = f2bf(f1.w);
  *(short8*)(o + i) = v;
}

// ---------------- prep: W[H,D,DH] -> Wt[N,K] bf16 (B^T layout) ----------------
__global__ __launch_bounds__(256) void wt_kernel(const float* __restrict__ Wq, const float* __restrict__ Wk,
                                                 const float* __restrict__ Wv, u16* __restrict__ Wt) {
  const int d0 = blockIdx.x * 64;
  const int h = blockIdx.y;
  const int qkv = blockIdx.z;
  const float* W = (qkv == 0) ? Wq : ((qkv == 1) ? Wk : Wv);
  __shared__ float tile[64][65];
  const int t = threadIdx.x;
  {
    int e = t & 63, dr = t >> 6;
#pragma unroll
    for (int p = 0; p < 16; ++p) {
      int dd = dr + p * 4;
      tile[dd][e] = W[((long)h * D_ + d0 + dd) * DH_ + e];
    }
  }
  __syncthreads();
  {
    int dd = t & 63, er = t >> 6;
#pragma unroll
    for (int p = 0; p < 16; ++p) {
      int ee = er + p * 4;
      long n = (long)qkv * 1024 + h * 64 + ee;
      Wt[n * K_ + d0 + dd] = f2bf(tile[dd][ee]);
    }
  }
}

// ---------------- prep: pack biases into [3072] fp32 ----------------
__global__ __launch_bounds__(256) void bias_kernel(const float* __restrict__ bq, const float* __restrict__ bk,
                                                   const float* __restrict__ bv, float* __restrict__ bias) {
  int i = blockIdx.x * 256 + threadIdx.x;
  if (i < 3072) {
    const float* src = (i < 1024) ? bq : ((i < 2048) ? bk : bv);
    bias[i] = src[i & 1023];
  }
}

// ---------------- QKV GEMM: 128x256 tile, BK=32, dbuf, 2 blocks/CU ----------------
// (frozen: best measured variant, r5 = 207us; structure changes exhausted their gains)

__device__ __forceinline__ void stage_a(const u16* __restrict__ g, u16* l, int tid, int k0) {
  const int r = tid >> 2;                               // row 0..127
  const int gch = (tid & 3) ^ ((tid >> 3) & 3);         // swizzled global k-chunk for phys slot tid&3
  gload_lds16(g + (long)r * K_ + k0 + gch * 8, l + tid * 8);
}

__device__ __forceinline__ void stage_b(const u16* __restrict__ g, u16* l, int tid, int k0) {
  const int r = tid >> 2;
  const int gch = (tid & 3) ^ ((tid >> 3) & 3);
  const u16* src = g + (long)r * K_ + k0 + gch * 8;
  gload_lds16(src, l + tid * 8);                        // rows 0..127
  gload_lds16(src + 128L * K_, l + 4096 + tid * 8);     // rows 128..255
}

__global__ __launch_bounds__(512, 4) void qkv_gemm(const u16* __restrict__ A, const u16* __restrict__ Bt,
                                                   const float* __restrict__ bias,
                                                   u16* __restrict__ qb, u16* __restrict__ kb,
                                                   u16* __restrict__ vbt) {
  __shared__ alignas(16) u16 Ab[2][128 * 32];   // 8 KB each
  __shared__ alignas(16) u16 Bb[2][256 * 32];   // 16 KB each
  const int tid = threadIdx.x, wid = tid >> 6, lane = tid & 63, quad = lane >> 4, l16 = lane & 15;
  const int wr = wid >> 2, wc = wid & 3;        // 2M x 4N wave grid

  // XCD swizzle: 1752 blocks = 8 * 219 exactly
  const int wg = (blockIdx.x & 7) * 219 + (blockIdx.x >> 3);
  const int mt = wg / 12, nt = wg - mt * 12;
  const long m0 = (long)mt * 128, n0 = (long)nt * 256;
  const u16* Ag = A + m0 * K_;
  const u16* Bg = Bt + n0 * K_;

  f32x4 acc[4][4];
#pragma unroll
  for (int mi = 0; mi < 4; ++mi)
#pragma unroll
    for (int ni = 0; ni < 4; ++ni) { f32x4 z = {0.f, 0.f, 0.f, 0.f}; acc[mi][ni] = z; }

  const int sw = quad ^ ((l16 >> 1) & 3);  // frag-read phys chunk (inverse of staging swizzle)
  const int arow = wr * 64 + l16;
  const int brow = wc * 64 + l16;

  // prologue: stage K-tile 0 into buf0
  stage_a(Ag, Ab[0], tid, 0);
  stage_b(Bg, Bb[0], tid, 0);
  __syncthreads();

#pragma unroll 1
  for (int t = 0; t < 32; t += 2) {
    // step 0: compute buf0 (tile t), stage tile t+1 -> buf1
    {
      stage_a(Ag, Ab[1], tid, (t + 1) * 32);
      stage_b(Bg, Bb[1], tid, (t + 1) * 32);
      const short8* Av = (const short8*)Ab[0];
      const short8* Bv = (const short8*)Bb[0];
      short8 a[4], b[4];
#pragma unroll
      for (int mi = 0; mi < 4; ++mi) a[mi] = Av[(arow + mi * 16) * 4 + sw];
#pragma unroll
      for (int ni = 0; ni < 4; ++ni) b[ni] = Bv[(brow + ni * 16) * 4 + sw];
#pragma unroll
      for (int mi = 0; mi < 4; ++mi)
#pragma unroll
        for (int ni = 0; ni < 4; ++ni)
          acc[mi][ni] = __builtin_amdgcn_mfma_f32_16x16x32_bf16(a[mi], b[ni], acc[mi][ni], 0, 0, 0);
      __syncthreads();
    }
    // step 1: compute buf1 (tile t+1), stage tile t+2 -> buf0 (unless done)
    {
      if (t + 2 < 32) {
        stage_a(Ag, Ab[0], tid, (t + 2) * 32);
        stage_b(Bg, Bb[0], tid, (t + 2) * 32);
      }
      const short8* Av = (const short8*)Ab[1];
      const short8* Bv = (const short8*)Bb[1];
      short8 a[4], b[4];
#pragma unroll
      for (int mi = 0; mi < 4; ++mi) a[mi] = Av[(arow + mi * 16) * 4 + sw];
#pragma unroll
      for (int ni = 0; ni < 4; ++ni) b[ni] = Bv[(brow + ni * 16) * 4 + sw];
#pragma unroll
      for (int mi = 0; mi < 4; ++mi)
#pragma unroll
        for (int ni = 0; ni < 4; ++ni)
          acc[mi][ni] = __builtin_amdgcn_mfma_f32_16x16x32_bf16(a[mi], b[ni], acc[mi][ni], 0, 0, 0);
      __syncthreads();
    }
  }

  // epilogue: += bias; scatter q/k to [B,H,S,DH], v to e-major [B,H,DH,ST_]
  const long nb = n0 + wc * 64;
  const int h = (int)((nb >> 6) & 15);
  const int qkvsel = (int)(nb >> 10);
  float bv4[4];
#pragma unroll
  for (int ni = 0; ni < 4; ++ni) bv4[ni] = bias[nb + ni * 16 + l16];

  if (qkvsel == 2) {
#pragma unroll
    for (int mi = 0; mi < 4; ++mi) {
#pragma unroll
      for (int r = 0; r < 4; ++r) {
        long m = m0 + wr * 64 + mi * 16 + quad * 4 + r;
        if (m < M_) {
          unsigned bi = (unsigned)m / (unsigned)S_;
          unsigned si = (unsigned)m - bi * (unsigned)S_;
          long base = ((long)(bi * H_ + h) * DH_) * ST_ + si;
#pragma unroll
          for (int ni = 0; ni < 4; ++ni) {
            float v = acc[mi][ni][r] + bv4[ni];
            vbt[base + (long)(ni * 16 + l16) * ST_] = f2bf(v);
          }
        }
      }
    }
  } else {
    u16* dst = (qkvsel == 0) ? qb : kb;
#pragma unroll
    for (int mi = 0; mi < 4; ++mi) {
#pragma unroll
      for (int r = 0; r < 4; ++r) {
        long m = m0 + wr * 64 + mi * 16 + quad * 4 + r;
        if (m < M_) {
          unsigned bi = (unsigned)m / (unsigned)S_;
          unsigned si = (unsigned)m - bi * (unsigned)S_;
          long base = ((long)(bi * H_ + h) * S_ + si) * DH_;
#pragma unroll
          for (int ni = 0; ni < 4; ++ni) {
            float v = acc[mi][ni][r] + bv4[ni];
            dst[base + ni * 16 + l16] = f2bf(v);
          }
        }
      }
    }
  }
}

// ---------------- flash attention, QBLK=128 (4 waves x 32 rows), fixed-max softmax ----------------
// Per K-tile iteration each wave now runs 32 MFMA against the same 2 barriers / 32KB staging:
// kf frags shared across both 16-row groups (8 ds_read -> 16 QK MFMA), vf shared (8 -> 16 PV MFMA).
// Grid halves to 5 Q-tiles per (b,h) -> K/V re-fetch traffic and barrier count both halve.
// Staging geometry and all fragment/swizzle math identical to the proven 64-row version.
__global__ __launch_bounds__(256) void attn_kernel(const u16* __restrict__ qb, const u16* __restrict__ kb,
                                                   const u16* __restrict__ vbt, float* __restrict__ out) {
  __shared__ alignas(16) u16 Ks[64 * 64];
  __shared__ alignas(16) u16 Vs[64 * 64];
  __shared__ alignas(16) u16 Ps[4 * 32 * 72];
  const int tid = threadIdx.x, wave = tid >> 6, lane = tid & 63, quad = lane >> 4, l16 = lane & 15;
  const int qt = blockIdx.x, h = blockIdx.y, b = blockIdx.z;
  const long bh = (long)b * H_ + h;
  const u16* qp = qb + bh * S_ * DH_;
  const u16* kp = kb + bh * S_ * DH_;
  const u16* vtp = vbt + bh * DH_ * ST_;
  const int q0 = qt * 128;

  short8 qf[2][2];
#pragma unroll
  for (int g = 0; g < 2; ++g) {
    int row = q0 + wave * 32 + g * 16 + l16;
    const short8* qv = (const short8*)(qp + (long)row * DH_);
    qf[g][0] = qv[quad];
    qf[g][1] = qv[4 + quad];
  }

  f32x4 O[2][4];
#pragma unroll
  for (int g = 0; g < 2; ++g)
#pragma unroll
    for (int et = 0; et < 4; ++et) { f32x4 z = {0.f, 0.f, 0.f, 0.f}; O[g][et] = z; }
  float lp[2][4] = {{0.f, 0.f, 0.f, 0.f}, {0.f, 0.f, 0.f, 0.f}};

  // staging geometry: pass p covers rows 32p..32p+31; lane handles row (tid>>3)+32p,
  // fetching global chunk (tid&7)^(row&7) into LDS linear slot tid&7.
  const int srow0 = tid >> 3;
  const int slot = tid & 7;
  const int s0 = quad ^ (l16 & 7);  // frag-read slot for chunk `quad` at row with (row&7)==(l16&7)

  u16* Pw = Ps + wave * 32 * 72;
  const short8* Pv8 = (const short8*)(Ps + wave * 32 * 72);

  for (int kt = 0; kt < 10; ++kt) {
    const int t0 = kt * 64;
    __syncthreads();
#pragma unroll
    for (int p = 0; p < 2; ++p) {
      int row = srow0 + 32 * p;
      int gch = slot ^ (row & 7);
      gload_lds16(kp + (long)(t0 + row) * DH_ + gch * 8, &Ks[(tid + 256 * p) * 8]);
      gload_lds16(vtp + (long)row * ST_ + t0 + gch * 8, &Vs[(tid + 256 * p) * 8]);
    }
    __syncthreads();

    // QK^T for both row groups, kf frags shared; p written to LDS inside the loop
    const short8* Kv8 = (const short8*)Ks;
#pragma unroll
    for (int jt = 0; jt < 4; ++jt) {
      short8 kf0 = Kv8[(16 * jt + l16) * 8 + s0];
      short8 kf1 = Kv8[(16 * jt + l16) * 8 + ((quad + 4) ^ (l16 & 7))];
      bool valid = (t0 + 16 * jt + l16) < S_;
#pragma unroll
      for (int g = 0; g < 2; ++g) {
        f32x4 sacc = {0.f, 0.f, 0.f, 0.f};
        sacc = __builtin_amdgcn_mfma_f32_16x16x32_bf16(qf[g][0], kf0, sacc, 0, 0, 0);
        sacc = __builtin_amdgcn_mfma_f32_16x16x32_bf16(qf[g][1], kf1, sacc, 0, 0, 0);
#pragma unroll
        for (int r = 0; r < 4; ++r) {
          float e = valid ? exp2f(sacc[r] * SCALE2 - CMAX) : 0.f;
          lp[g][r] += e;
          Pw[(g * 16 + quad * 4 + r) * 72 + 16 * jt + l16] = f2bf(e);
        }
      }
    }

    // PV: vf frags shared across both row groups; wave-private P, no barrier needed
    const short8* Vv8 = (const short8*)Vs;
#pragma unroll
    for (int ks = 0; ks < 2; ++ks) {
      short8 pa0 = Pv8[(0 + l16) * 9 + ks * 4 + quad];
      short8 pa1 = Pv8[(16 + l16) * 9 + ks * 4 + quad];
#pragma unroll
      for (int et = 0; et < 4; ++et) {
        short8 vf = Vv8[(16 * et + l16) * 8 + ((ks * 4 + quad) ^ (l16 & 7))];
        O[0][et] = __builtin_amdgcn_mfma_f32_16x16x32_bf16(pa0, vf, O[0][et], 0, 0, 0);
        O[1][et] = __builtin_amdgcn_mfma_f32_16x16x32_bf16(pa1, vf, O[1][et], 0, 0, 0);
      }
    }
  }

  // reduce row sums across the quad's 16 lanes, normalize, store fp32 [B,S,H*DH]
  float inv[2][4];
#pragma unroll
  for (int g = 0; g < 2; ++g)
#pragma unroll
    for (int r = 0; r < 4; ++r) {
      float s = lp[g][r];
      s += __shfl_xor(s, 1);
      s += __shfl_xor(s, 2);
      s += __shfl_xor(s, 4);
      s += __shfl_xor(s, 8);
      inv[g][r] = 1.0f / s;
    }
#pragma unroll
  for (int g = 0; g < 2; ++g)
#pragma unroll
    for (int et = 0; et < 4; ++et)
#pragma unroll
      for (int r = 0; r < 4; ++r) {
        int s = q0 + wave * 32 + g * 16 + quad * 4 + r;
        if (s < S_) out[((long)b * S_ + s) * (H_ * DH_) + (long)h * DH_ + et * 16 + l16] = O[g][et][r] * inv[g][r];
      }
}

extern "C" void kernel_launch(void* const* d_in, const int* in_sizes, int n_in,
                              void* d_out, int out_size, void* d_ws, size_t ws_size,
                              hipStream_t stream) {
  const float* hs = (const float*)d_in[0];
  const float* Wq = (const float*)d_in[1];
  const float* bq = (const float*)d_in[2];
  const float* Wk = (const float*)d_in[3];
  const float* bk = (const float*)d_in[4];
  const float* Wv = (const float*)d_in[5];
  const float* bv = (const float*)d_in[6];
  float* out = (float*)d_out;

  u16* Abf = (u16*)d_ws;                                   // [MP2_, K_] bf16
  u16* Wt = Abf + (size_t)MP2_ * K_;                       // [N_, K_] bf16
  float* bias = (float*)(Wt + (size_t)N_ * K_);            // [N_] fp32
  u16* qb = (u16*)(bias + N_);                             // [BHROWS_, DH_] bf16
  u16* kb = qb + (size_t)BHROWS_ * DH_;                    // [BHROWS_, DH_] bf16
  u16* vbt = kb + (size_t)BHROWS_ * DH_;                   // [B*H, DH_, ST_] bf16 (e-major)

  cvt_hidden<<<dim3(9344), dim3(256), 0, stream>>>(hs, Abf);
  wt_kernel<<<dim3(16, 16, 3), dim3(256), 0, stream>>>(Wq, Wk, Wv, Wt);
  bias_kernel<<<dim3(12), dim3(256), 0, stream>>>(bq, bk, bv, bias);
  qkv_gemm<<<dim3(1752), dim3(512), 0, stream>>>(Abf, Wt, bias, qb, kb, vbt);
  attn_kernel<<<dim3(5, 16, 32), dim3(256), 0, stream>>>(qb, kb, vbt, out);
}